// Round 7
// baseline (178.148 us; speedup 1.0000x reference)
//
#include <hip/hip_runtime.h>
#include <hip/hip_bf16.h>
#include <math.h>

#define NN 2048      // nodes
#define NE 4096      // edges
#define D 128
#define NODE_K 1024
#define EDGE_K 2048
#define CAP 64       // per-node incident-edge list capacity (mean degree 4)
#define ROWS 16      // rows per block, h_qkv
#define ROWS2 8      // rows per block, o_mlp
#define BT 512       // threads for fused GEMM kernels

typedef const __hip_bfloat16* bfp;
__device__ __forceinline__ float b2f(__hip_bfloat16 x) { return __bfloat162float(x); }

// dual-path loads: f=1 -> fp32 input, f=0 -> bf16 input (bf16->fp32 is exact)
__device__ __forceinline__ float ldx(const void* p, size_t i, int f) {
  return f ? ((const float*)p)[i] : b2f(((bfp)p)[i]);
}
__device__ __forceinline__ float4 ldx4(const void* p, size_t i4, int f) {
  if (f) return ((const float4*)p)[i4];
  ushort4 u = ((const ushort4*)p)[i4];
  float4 r;
  r.x = b2f(*(const __hip_bfloat16*)&u.x);
  r.y = b2f(*(const __hip_bfloat16*)&u.y);
  r.z = b2f(*(const __hip_bfloat16*)&u.z);
  r.w = b2f(*(const __hip_bfloat16*)&u.w);
  return r;
}

// per-block dtype detect from first 4096 halves of node_features (8 KB, L2-hot)
__device__ __forceinline__ int detect_f(const unsigned short* raw, int* s4) {
  int t = threadIdx.x;
  int weird = 0;
  for (int i = t; i < 4096; i += blockDim.x) {
    unsigned int bits = ((unsigned int)raw[i]) << 16;
    float x = __uint_as_float(bits);
    float ax = fabsf(x);
    if (!(ax <= 1e3f) || (x != 0.f && ax < 1e-12f)) weird++;  // nan/inf/huge/denorm
  }
  #pragma unroll
  for (int m = 32; m >= 1; m >>= 1) weird += __shfl_xor(weird, m);
  int nw = (int)blockDim.x >> 6;
  if ((t & 63) == 0) s4[t >> 6] = weird;
  __syncthreads();
  int tot = 0;
  for (int i = 0; i < nw; ++i) tot += s4[i];
  return (tot > 200) ? 1 : 0;  // 1 => inputs are fp32
}

// ---------- K1: router scores (fp64 acc) + zero deg + publish flag ----------
#define SCORE_BLOCKS ((NN + NE) / 4)
__global__ __launch_bounds__(256) void scores_kernel(
    const void* __restrict__ rawNF, const void* __restrict__ rawEF,
    const void* __restrict__ rawWRN, const void* __restrict__ rawWRE,
    float* __restrict__ ns, float* __restrict__ es,
    int* __restrict__ deg, int* __restrict__ flag) {
  __shared__ int s4[16];
  int b = blockIdx.x, t = threadIdx.x;
  int f = detect_f((const unsigned short*)rawNF, s4);
  if (b == SCORE_BLOCKS) {  // aux block: zero deg, publish flag for K3/K5
    if (t == 0) flag[0] = f;
    for (int i = t; i < NN; i += 256) deg[i] = 0;
    return;
  }
  int wid = b * 4 + (t >> 6), lane = t & 63;
  const void* base; const void* w; float* out; size_t r0;
  if (wid < NN) { base = rawNF; r0 = (size_t)wid * D;        w = rawWRN; out = ns + wid; }
  else { int r = wid - NN; base = rawEF; r0 = (size_t)r * D; w = rawWRE; out = es + r; }
  double p = (double)ldx(base, r0 + lane, f) * (double)ldx(w, lane, f)
           + (double)ldx(base, r0 + lane + 64, f) * (double)ldx(w, lane + 64, f);
  #pragma unroll
  for (int m = 32; m >= 1; m >>= 1) p += __shfl_xor(p, m);
  if (lane == 0) *out = (float)p;
}

// ---------- K2: node rank + edge rank + incident lists (independent sections) ----
#define NMB (NN / 4)
#define EMB (NE / 4)
__global__ __launch_bounds__(256) void mask_lists_kernel(
    const float* __restrict__ ns, const float* __restrict__ es,
    const int* __restrict__ src, const int* __restrict__ dst,
    int* __restrict__ node_mask, int* __restrict__ edge_topk,
    int* __restrict__ deg, int* __restrict__ lists) {
  __shared__ float s[NE];  // 16 KB (node section uses first NN)
  int b = blockIdx.x, t = threadIdx.x;
  if (b < NMB) {           // exact top-k rank, stable ties (== lax.top_k)
    for (int i = t; i < NN; i += 256) s[i] = ns[i];
    __syncthreads();
    int i = b * 4 + (t >> 6), lane = t & 63;
    float si = s[i];
    int rank = 0;
    for (int j = lane; j < NN; j += 64) {
      float sj = s[j];
      rank += (sj > si) || (sj == si && j < i);
    }
    #pragma unroll
    for (int m = 32; m >= 1; m >>= 1) rank += __shfl_xor(rank, m);
    if (lane == 0) node_mask[i] = (rank < NODE_K) ? 1 : 0;
  } else if (b < NMB + EMB) {
    for (int i = t; i < NE; i += 256) s[i] = es[i];
    __syncthreads();
    int i = (b - NMB) * 4 + (t >> 6), lane = t & 63;
    float si = s[i];
    int rank = 0;
    for (int j = lane; j < NE; j += 64) {
      float sj = s[j];
      rank += (sj > si) || (sj == si && j < i);
    }
    #pragma unroll
    for (int m = 32; m >= 1; m >>= 1) rank += __shfl_xor(rank, m);
    if (lane == 0) edge_topk[i] = (rank < EDGE_K) ? 1 : 0;
  } else {                 // incident-edge lists (deg zeroed in K1)
    int e = (b - NMB - EMB) * 256 + t;
    if (e < NE) {
      int sn = src[e], dn = dst[e];
      int p = atomicAdd(&deg[sn], 1);
      if (p >= 0 && p < CAP) lists[sn * CAP + p] = e;
      if (dn != sn) {
        p = atomicAdd(&deg[dn], 1);
        if (p >= 0 && p < CAP) lists[dn * CAP + p] = e;
      }
    }
  }
}

// ---------- shared GEMM pass: acc[R] += As @ Wg(128x128, dual-path staged) -------
// thread t: j = t&127 (output col), rg = t>>7 (row group of R rows)
template <int R>
__device__ __forceinline__ void gemm_pass(const void* __restrict__ Wg, int f,
                                          float* __restrict__ Wl,
                                          const float* __restrict__ As,
                                          int j, int rg, float acc[R]) {
  for (int half = 0; half < 2; ++half) {
    __syncthreads();
    for (int i = threadIdx.x; i < 64 * D / 4; i += BT)
      ((float4*)Wl)[i] = ldx4(Wg, half * (64 * D / 4) + i, f);
    __syncthreads();
    #pragma unroll 4
    for (int k4 = 0; k4 < 16; ++k4) {
      int kr = k4 * 4;
      int k0 = half * 64 + kr;
      float w0 = Wl[(kr + 0) * D + j];
      float w1 = Wl[(kr + 1) * D + j];
      float w2 = Wl[(kr + 2) * D + j];
      float w3 = Wl[(kr + 3) * D + j];
      #pragma unroll
      for (int r = 0; r < R; ++r) {
        float4 a = ((const float4*)As)[((rg * R + r) * D + k0) >> 2];
        acc[r] += a.x * w0 + a.y * w1 + a.z * w2 + a.w * w3;
      }
    }
  }
}

// ---------- K3: gather -> h -> one of q/k/v (blockIdx.y selects) ----------
__global__ __launch_bounds__(BT) void h_qkv_kernel(
    const void* __restrict__ rawEF, const void* __restrict__ rawNF,
    const int* __restrict__ src, const int* __restrict__ dst,
    const int* __restrict__ node_mask, const int* __restrict__ edge_topk,
    const int* __restrict__ flag,
    const void* __restrict__ WE, const void* __restrict__ WN,
    const void* __restrict__ WQ, const void* __restrict__ WK,
    const void* __restrict__ WV, float* __restrict__ qkv) {
  __shared__ __align__(16) float Wl[64 * D];   // 32 KB
  __shared__ __align__(16) float A1[ROWS * D]; // efm, reused as h
  __shared__ __align__(16) float A2[ROWS * D]; // nsum
  int t = threadIdx.x;
  int row0 = blockIdx.x * ROWS;
  int f = flag[0];
  {
    int i = t;                       // exactly ROWS*D/4 = 512 float4 slots
    int e = row0 + (i >> 5), c4 = i & 31;
    int sn = src[e], dn = dst[e];
    float m = (edge_topk[e] && node_mask[sn] && node_mask[dn]) ? 1.f : 0.f;
    float4 ef4 = ldx4(rawEF, (size_t)e * 32 + c4, f);
    ((float4*)A1)[i] = make_float4(m * ef4.x, m * ef4.y, m * ef4.z, m * ef4.w);
    float4 s4 = ldx4(rawNF, (size_t)sn * 32 + c4, f);
    float4 d4 = ldx4(rawNF, (size_t)dn * 32 + c4, f);
    ((float4*)A2)[i] = make_float4(s4.x + d4.x, s4.y + d4.y, s4.z + d4.z, s4.w + d4.w);
  }
  int j = t & 127, rg = t >> 7;
  float acc[4] = {0, 0, 0, 0};
  gemm_pass<4>(WE, f, Wl, A1, j, rg, acc);   // h += efm @ w_e
  gemm_pass<4>(WN, f, Wl, A2, j, rg, acc);   // h += nsum @ w_n
  __syncthreads();
  #pragma unroll
  for (int r = 0; r < 4; ++r) A1[(rg * 4 + r) * D + j] = acc[r];  // A1 := h
  int sel = blockIdx.y;
  const void* Wsel = (sel == 0) ? WQ : (sel == 1) ? WK : WV;
  float a2[4] = {0, 0, 0, 0};
  gemm_pass<4>(Wsel, f, Wl, A1, j, rg, a2);  // leading sync makes h visible
  float* C = qkv + (size_t)sel * NE * D;
  #pragma unroll
  for (int r = 0; r < 4; ++r) C[(size_t)(row0 + rg * 4 + r) * D + j] = a2[r];
}

// ---------- K4: sparse edge attention, one block (128 thr) per query edge --------
__global__ void attn_kernel(const float* __restrict__ q, const float* __restrict__ k,
                            const float* __restrict__ v, const int* __restrict__ src,
                            const int* __restrict__ dst, const int* __restrict__ deg,
                            const int* __restrict__ lists, float* __restrict__ ao) {
  int e = blockIdx.x;
  int j = threadIdx.x;  // head = j/32, d = j%32 (shfl_xor<32 stays in-head)
  float qj = q[e * D + j];
  int sn = src[e], dn = dst[e];
  float m = -1e30f, l = 0.f, acc = 0.f;
  const float scale = 0.17677669529663687f;  // 1/sqrt(32)
  int degA = max(0, min(deg[sn], CAP));
  for (int i = 0; i < degA; ++i) {
    int f = lists[sn * CAP + i];
    float p = qj * k[f * D + j];
    p += __shfl_xor(p, 16); p += __shfl_xor(p, 8); p += __shfl_xor(p, 4);
    p += __shfl_xor(p, 2);  p += __shfl_xor(p, 1);
    float s = p * scale;
    float vj = v[f * D + j];
    float mn = fmaxf(m, s);
    float corr = expf(m - mn);
    float w = expf(s - mn);
    l = l * corr + w;
    acc = acc * corr + w * vj;
    m = mn;
  }
  if (dn != sn) {
    int degB = max(0, min(deg[dn], CAP));
    for (int i = 0; i < degB; ++i) {
      int f = lists[dn * CAP + i];
      if (src[f] == sn || dst[f] == sn) continue;  // already in list A
      float p = qj * k[f * D + j];
      p += __shfl_xor(p, 16); p += __shfl_xor(p, 8); p += __shfl_xor(p, 4);
      p += __shfl_xor(p, 2);  p += __shfl_xor(p, 1);
      float s = p * scale;
      float vj = v[f * D + j];
      float mn = fmaxf(m, s);
      float corr = expf(m - mn);
      float w = expf(s - mn);
      l = l * corr + w;
      acc = acc * corr + w * vj;
      m = mn;
    }
  }
  ao[e * D + j] = acc / fmaxf(l, 1e-37f);
}

// ---------- K5: o = ao@WO; x = gelu(o@W1+b1); logits = x@W2+b2 ----------
__global__ __launch_bounds__(BT) void o_mlp_logits_kernel(
    const float* __restrict__ ao, const void* __restrict__ WO,
    const void* __restrict__ W1, const void* __restrict__ B1,
    const void* __restrict__ W2, const void* __restrict__ B2,
    const int* __restrict__ flag, void* __restrict__ out) {
  __shared__ __align__(16) float Wl[64 * D];    // 32 KB
  __shared__ __align__(16) float Al[ROWS2 * D]; // ao rows, reused as x (4 KB)
  __shared__ __align__(16) float Bl[ROWS2 * D]; // o rows (4 KB)
  int t = threadIdx.x;
  int row0 = blockIdx.x * ROWS2;
  int f = flag[0];
  if (t < ROWS2 * D / 4)
    ((float4*)Al)[t] = ((const float4*)ao)[(size_t)blockIdx.x * (ROWS2 * D / 4) + t];
  int j = t & 127, rg = t >> 7;
  float acc[2] = {0, 0};
  gemm_pass<2>(WO, f, Wl, Al, j, rg, acc);   // o = ao @ w_o (leading sync covers Al)
  __syncthreads();
  #pragma unroll
  for (int r = 0; r < 2; ++r) Bl[(rg * 2 + r) * D + j] = acc[r];
  float acc2[2] = {0, 0};
  gemm_pass<2>(W1, f, Wl, Bl, j, rg, acc2);  // leading sync makes Bl visible
  float bj = ldx(B1, j, f);
  __syncthreads();                           // all reads of Al done before overwrite
  #pragma unroll
  for (int r = 0; r < 2; ++r) {              // x = gelu(o@w1 + b1)
    float u = acc2[r] + bj;
    float inner = 0.7978845608028654f * (u + 0.044715f * u * u * u);
    Al[(rg * 2 + r) * D + j] = 0.5f * u * (1.f + tanhf(inner));
  }
  __syncthreads();
  for (int i = t; i < D * 16; i += BT) Wl[i] = ldx(W2, i, f);
  __syncthreads();
  if (t < ROWS2 * 16) {                      // logits = x @ w2 + b2
    int r = t >> 4, c = t & 15;
    float s = 0.f;
    for (int kk = 0; kk < D; ++kk) s += Al[r * D + kk] * Wl[kk * 16 + c];
    s += ldx(B2, c, f);
    int idx = (row0 + r) * 16 + c;
    if (f) ((float*)out)[idx] = s;
    else ((__hip_bfloat16*)out)[idx] = __float2bfloat16(s);
  }
}

extern "C" void kernel_launch(void* const* d_in, const int* in_sizes, int n_in,
                              void* d_out, int out_size, void* d_ws, size_t ws_size,
                              hipStream_t stream) {
  const int* eidx = (const int*)d_in[2];
  const int* src = eidx;
  const int* dst = eidx + NE;

  size_t off = 0;
  char* base = (char*)d_ws;
  auto alloc = [&](size_t nbytes) -> void* {
    void* p = base + off;
    off += (nbytes + 255) & ~(size_t)255;
    return p;
  };
  int* flag        = (int*)alloc(256);
  float* ns        = (float*)alloc(NN * sizeof(float));
  float* es        = (float*)alloc(NE * sizeof(float));
  int* node_mask   = (int*)alloc(NN * sizeof(int));
  int* edge_topk   = (int*)alloc(NE * sizeof(int));
  int* deg         = (int*)alloc(NN * sizeof(int));
  int* lists       = (int*)alloc((size_t)NN * CAP * sizeof(int));
  float* qkv       = (float*)alloc((size_t)3 * NE * D * sizeof(float));
  float* ao        = (float*)alloc((size_t)NE * D * sizeof(float));
  float* qb = qkv, *kb = qkv + NE * D, *vb = qkv + 2 * NE * D;

  // K1: scores + zero deg + flag
  scores_kernel<<<SCORE_BLOCKS + 1, 256, 0, stream>>>(
      d_in[0], d_in[1], d_in[3], d_in[4], ns, es, deg, flag);
  // K2: node rank + edge rank + incident lists
  mask_lists_kernel<<<NMB + EMB + NE / 256, 256, 0, stream>>>(
      ns, es, src, dst, node_mask, edge_topk, deg, lists);
  // K3: gather -> h -> q/k/v (y = which projection)
  h_qkv_kernel<<<dim3(NE / ROWS, 3), BT, 0, stream>>>(
      d_in[1], d_in[0], src, dst, node_mask, edge_topk, flag,
      d_in[5], d_in[6], d_in[7], d_in[8], d_in[9], qkv);
  // K4: sparse attention
  attn_kernel<<<NE, 128, 0, stream>>>(qb, kb, vb, src, dst, deg, lists, ao);
  // K5: epilogue
  o_mlp_logits_kernel<<<NE / ROWS2, BT, 0, stream>>>(
      ao, d_in[10], d_in[11], d_in[12], d_in[13], d_in[14], flag, d_out);
}